// Round 3
// baseline (2118.716 us; speedup 1.0000x reference)
//
#include <hip/hip_runtime.h>
#include <math.h>

#define NN 50000
#define NE 800000
#define NCOLS 1088   // 256 q | 256 k | 256 v | 256 qt | 64 skip

typedef long long i64;

// ---------------- edge-index dtype probe + extraction ----------------
__global__ void detect_i64(const int* __restrict__ ei32, int* __restrict__ flag) {
  int i = blockIdx.x * blockDim.x + threadIdx.x;
  if (i < 2048) {
    if (ei32[2 * i + 1] != 0) atomicOr(flag, 1);  // 1 -> data is int32
  }
}

__global__ void extract_edges(const void* __restrict__ ei, const int* __restrict__ flag,
                              int* __restrict__ src32, int* __restrict__ dst32, int ne) {
  int is32 = *flag;
  int i = blockIdx.x * blockDim.x + threadIdx.x;
  int st = gridDim.x * blockDim.x;
  if (is32) {
    const int* p = (const int*)ei;
    for (; i < ne; i += st) { src32[i] = p[i]; dst32[i] = p[ne + i]; }
  } else {
    const i64* p = (const i64*)ei;
    for (; i < ne; i += st) { src32[i] = (int)p[i]; dst32[i] = (int)p[ne + i]; }
  }
}

// ---------------- CSR build ----------------
__global__ void hist_kernel(const int* __restrict__ dst, int* __restrict__ deg, int ne) {
  int i = blockIdx.x * blockDim.x + threadIdx.x;
  int st = gridDim.x * blockDim.x;
  for (; i < ne; i += st) atomicAdd(&deg[dst[i]], 1);
}

__global__ void scan_kernel(const int* __restrict__ deg, int* __restrict__ row_ptr, int n) {
  __shared__ int buf[1024];
  int t = threadIdx.x;
  int carry = 0;
  if (t == 0) row_ptr[0] = 0;
  for (int base = 0; base < n; base += 1024) {
    int v = (base + t < n) ? deg[base + t] : 0;
    buf[t] = v;
    __syncthreads();
    for (int off = 1; off < 1024; off <<= 1) {
      int x = (t >= off) ? buf[t - off] : 0;
      __syncthreads();
      buf[t] += x;
      __syncthreads();
    }
    if (base + t < n) row_ptr[base + t + 1] = carry + buf[t];
    carry += buf[1023];
    __syncthreads();
  }
}

__global__ void scatter_kernel(const int* __restrict__ src, const int* __restrict__ dst,
                               const int* __restrict__ row_ptr, int* __restrict__ cursor,
                               int* __restrict__ src_sorted, int* __restrict__ eid_sorted, int ne) {
  int i = blockIdx.x * blockDim.x + threadIdx.x;
  int st = gridDim.x * blockDim.x;
  for (; i < ne; i += st) {
    int d = dst[i];
    int pos = row_ptr[d] + atomicAdd(&cursor[d], 1);
    src_sorted[pos] = src[i];
    eid_sorted[pos] = i;
  }
}

// Deterministic order: sort each node's edge list by eid (insertion sort, deg ~16).
__global__ void sort_lists(const int* __restrict__ row_ptr, int* __restrict__ src_sorted,
                           int* __restrict__ eid_sorted, int n) {
  int node = blockIdx.x * blockDim.x + threadIdx.x;
  if (node >= n) return;
  int beg = row_ptr[node], end = row_ptr[node + 1];
  for (int a = beg + 1; a < end; ++a) {
    int e = eid_sorted[a], s = src_sorted[a];
    int b = a - 1;
    while (b >= beg && eid_sorted[b] > e) {
      eid_sorted[b + 1] = eid_sorted[b];
      src_sorted[b + 1] = src_sorted[b];
      --b;
    }
    eid_sorted[b + 1] = e; src_sorted[b + 1] = s;
  }
}

// ---------------- weight prep (all fp32) ----------------
// Wt layout: [col][k], col: <256 q (d*4+h), <512 k, <768 v, <1024 qt (ce*4+h), else skip
__global__ void prep_wt(const float* __restrict__ Wq, const float* __restrict__ Wk,
                        const float* __restrict__ Wv, const float* __restrict__ We,
                        const float* __restrict__ Wsk, float* __restrict__ Wt, int fin) {
  int i = blockIdx.x * blockDim.x + threadIdx.x;
  if (i >= NCOLS * fin) return;
  int col = i / fin, k = i % fin;
  float val;
  if (col < 768) {
    const float* W = (col < 256) ? Wq : (col < 512) ? Wk : Wv;
    int idx = col & 255; int d = idx >> 2, h = idx & 3;
    val = W[k * 256 + h * 64 + d];
  } else if (col < 1024) {
    int idx = col - 768; int ce = idx >> 2, h = idx & 3;
    float a = 0.f;
    for (int d = 0; d < 64; ++d) a += Wq[k * 256 + h * 64 + d] * We[ce * 256 + h * 64 + d];
    val = a;
  } else {
    val = Wsk[k * 64 + (col - 1024)];
  }
  Wt[(size_t)col * fin + k] = val;
}

__global__ void prep_bias(const float* __restrict__ bq, const float* __restrict__ bk,
                          const float* __restrict__ bv, const float* __restrict__ We,
                          const float* __restrict__ bsk, float* __restrict__ bb) {
  int col = blockIdx.x * blockDim.x + threadIdx.x;
  if (col >= NCOLS) return;
  float val;
  if (col < 768) {
    const float* b = (col < 256) ? bq : (col < 512) ? bk : bv;
    int idx = col & 255;
    val = b[(idx & 3) * 64 + (idx >> 2)];
  } else if (col < 1024) {
    int idx = col - 768; int ce = idx >> 2, h = idx & 3;
    float a = 0.f;
    for (int d = 0; d < 64; ++d) a += bq[h * 64 + d] * We[ce * 256 + h * 64 + d];
    val = a;
  } else {
    val = bsk[col - 1024];
  }
  bb[col] = val;
}

// west layout: [ce][dd][h] = We[ce][h*64+dd], fp32, 64*64*4 = 16384 floats
__global__ void prep_west(const float* __restrict__ We, float* __restrict__ west) {
  int i = blockIdx.x * blockDim.x + threadIdx.x;
  if (i >= 16384) return;
  int h = i & 3, dd = (i >> 2) & 63, ce = i >> 8;
  west[i] = We[ce * 256 + h * 64 + dd];
}

// ---------------- fp32 node GEMM: out = X[N,fin] @ Wt^T + b ----------------
// 128x64 block tile, 16x16 threads, 8x4 micro-tile.
__global__ __launch_bounds__(256) void node_gemm_f32(
    const float* __restrict__ X, const float* __restrict__ Wt, const float* __restrict__ bb,
    float* __restrict__ q_tab, float* __restrict__ k_tab, float* __restrict__ v_tab,
    float* __restrict__ qt_tab, float* __restrict__ skip_tab, int n, int fin) {
  __shared__ __align__(16) float Xs[128][68];
  __shared__ __align__(16) float Ws[64][68];
  int tid = threadIdx.x;
  int tx = tid & 15, ty = tid >> 4;
  int m0 = blockIdx.x * 128, c0 = blockIdx.y * 64;
  float acc[8][4];
  #pragma unroll
  for (int i = 0; i < 8; ++i)
    #pragma unroll
    for (int j = 0; j < 4; ++j) acc[i][j] = 0.f;

  for (int k0 = 0; k0 < fin; k0 += 64) {
    #pragma unroll
    for (int p = 0; p < 8; ++p) {
      int r = ty + 16 * p;
      float4 xv = make_float4(0.f, 0.f, 0.f, 0.f);
      if (m0 + r < n) xv = *(const float4*)&X[(size_t)(m0 + r) * fin + k0 + tx * 4];
      *(float4*)&Xs[r][tx * 4] = xv;
    }
    #pragma unroll
    for (int p = 0; p < 4; ++p) {
      int r = ty + 16 * p;
      float4 wv = *(const float4*)&Wt[(size_t)(c0 + r) * fin + k0 + tx * 4];
      *(float4*)&Ws[r][tx * 4] = wv;
    }
    __syncthreads();
    #pragma unroll 4
    for (int kk = 0; kk < 64; kk += 4) {
      float4 a[8], b[4];
      #pragma unroll
      for (int i = 0; i < 8; ++i) a[i] = *(const float4*)&Xs[ty + 16 * i][kk];
      #pragma unroll
      for (int j = 0; j < 4; ++j) b[j] = *(const float4*)&Ws[tx + 16 * j][kk];
      #pragma unroll
      for (int i = 0; i < 8; ++i)
        #pragma unroll
        for (int j = 0; j < 4; ++j) {
          acc[i][j] = fmaf(a[i].x, b[j].x, acc[i][j]);
          acc[i][j] = fmaf(a[i].y, b[j].y, acc[i][j]);
          acc[i][j] = fmaf(a[i].z, b[j].z, acc[i][j]);
          acc[i][j] = fmaf(a[i].w, b[j].w, acc[i][j]);
        }
    }
    __syncthreads();
  }
  #pragma unroll
  for (int j = 0; j < 4; ++j) {
    int col = c0 + tx + 16 * j;
    float bias = bb[col];
    #pragma unroll
    for (int i = 0; i < 8; ++i) {
      int row = m0 + ty + 16 * i;
      if (row >= n) continue;
      float val = acc[i][j] + bias;
      if (col < 256)       q_tab[(size_t)row * 256 + col] = val;
      else if (col < 512)  k_tab[(size_t)row * 256 + col - 256] = val;
      else if (col < 768)  v_tab[(size_t)row * 256 + col - 512] = val;
      else if (col < 1024) qt_tab[(size_t)row * 256 + col - 768] = val;
      else                 skip_tab[(size_t)row * 64 + col - 1024] = val;
    }
  }
}

// ---------------- fused attention + post + skip + GN + GELU (fp32) ----------------
#define ONLINE(al, mh, sh, avh, awh, vv)            \
  {                                                 \
    float d_ = (al) - mh;                           \
    float e_ = __expf(-fabsf(d_));                  \
    float sc_ = d_ > 0.f ? e_ : 1.f;                \
    float pp_ = d_ > 0.f ? 1.f : e_;                \
    mh = fmaxf(mh, (al));                           \
    sh = sh * sc_ + pp_;                            \
    avh = avh * sc_ + pp_ * (vv);                   \
    awh = awh * sc_ + pp_ * eav;                    \
  }

__global__ __launch_bounds__(256) void attn_kernel_f32(
    const int* __restrict__ row_ptr, const int* __restrict__ src_sorted,
    const int* __restrict__ eid_sorted, const float* __restrict__ ea,
    const float* __restrict__ q_tab, const float* __restrict__ k_tab,
    const float* __restrict__ v_tab, const float* __restrict__ qt_tab,
    const float* __restrict__ skip_tab, const float* __restrict__ west,
    const float* __restrict__ gnw, const float* __restrict__ gnb,
    float* __restrict__ out, int n) {
  int tid = threadIdx.x;
  int wave = tid >> 6, lane = tid & 63;
  const float4* q4p = (const float4*)q_tab;
  const float4* t4p = (const float4*)qt_tab;
  const float4* k4p = (const float4*)k_tab;
  const float4* v4p = (const float4*)v_tab;
  const float4* w4p = (const float4*)west;
  float gw = gnw[lane], gb = gnb[lane];
  int ngroups = (n + 3) >> 2;
  for (int grp = blockIdx.x; grp < ngroups; grp += gridDim.x) {
    int node = grp * 4 + wave;
    if (node >= n) continue;
    float4 q4 = q4p[(size_t)node * 64 + lane];
    float4 t4 = t4p[(size_t)node * 64 + lane];
    float m0 = -INFINITY, m1 = -INFINITY, m2 = -INFINITY, m3 = -INFINITY;
    float s0 = 0.f, s1 = 0.f, s2 = 0.f, s3 = 0.f;
    float av0 = 0.f, av1 = 0.f, av2 = 0.f, av3 = 0.f;
    float aw0 = 0.f, aw1 = 0.f, aw2 = 0.f, aw3 = 0.f;
    int beg = row_ptr[node], end = row_ptr[node + 1];
    for (int j = beg; j < end; ++j) {
      int sidx = src_sorted[j];
      int eid = eid_sorted[j];
      float4 k4 = k4p[(size_t)sidx * 64 + lane];
      float4 v4 = v4p[(size_t)sidx * 64 + lane];
      float eav = ea[(size_t)eid * 64 + lane];
      float p0 = fmaf(t4.x, eav, q4.x * k4.x);
      float p1 = fmaf(t4.y, eav, q4.y * k4.y);
      float p2 = fmaf(t4.z, eav, q4.z * k4.z);
      float p3 = fmaf(t4.w, eav, q4.w * k4.w);
      #pragma unroll
      for (int off = 32; off >= 1; off >>= 1) {
        p0 += __shfl_xor(p0, off);
        p1 += __shfl_xor(p1, off);
        p2 += __shfl_xor(p2, off);
        p3 += __shfl_xor(p3, off);
      }
      p0 *= 0.125f; p1 *= 0.125f; p2 *= 0.125f; p3 *= 0.125f;
      ONLINE(p0, m0, s0, av0, aw0, v4.x);
      ONLINE(p1, m1, s1, av1, aw1, v4.y);
      ONLINE(p2, m2, s2, av2, aw2, v4.z);
      ONLINE(p3, m3, s3, av3, aw3, v4.w);
    }
    float i0 = s0 > 0.f ? 1.f / s0 : 0.f;
    float i1 = s1 > 0.f ? 1.f / s1 : 0.f;
    float i2 = s2 > 0.f ? 1.f / s2 : 0.f;
    float i3 = s3 > 0.f ? 1.f / s3 : 0.f;
    float wn0 = aw0 * i0, wn1 = aw1 * i1, wn2 = aw2 * i2, wn3 = aw3 * i3;
    float vsum = av0 * i0 + av1 * i1 + av2 * i2 + av3 * i3;
    float post = 0.f;
    for (int ce = 0; ce < 64; ++ce) {
      float w0 = __shfl(wn0, ce), w1 = __shfl(wn1, ce);
      float w2 = __shfl(wn2, ce), w3 = __shfl(wn3, ce);
      float4 wv = w4p[ce * 64 + lane];
      post = fmaf(w0, wv.x, post);
      post = fmaf(w1, wv.y, post);
      post = fmaf(w2, wv.z, post);
      post = fmaf(w3, wv.w, post);
    }
    float val = 0.25f * (vsum + post) + skip_tab[(size_t)node * 64 + lane];
    // GroupNorm: 16 groups of 4 consecutive channels = 4-lane groups
    float sm = val + __shfl_xor(val, 1);
    sm += __shfl_xor(sm, 2);
    float mu = sm * 0.25f;
    float dv = val - mu;
    float vq = dv * dv;
    float v2 = vq + __shfl_xor(vq, 1);
    v2 += __shfl_xor(v2, 2);
    float xn = dv * rsqrtf(v2 * 0.25f + 1e-5f);
    float y = xn * gw + gb;
    float g = 0.5f * y * (1.0f + erff(y * 0.70710678118654752f));
    out[(size_t)node * 64 + lane] = g;
  }
}

// ---------------- host ----------------
extern "C" void kernel_launch(void* const* d_in, const int* in_sizes, int n_in,
                              void* d_out, int out_size, void* d_ws, size_t ws_size,
                              hipStream_t stream) {
  (void)in_sizes; (void)n_in;
  const float* x = (const float*)d_in[0];
  const void* ei = d_in[1];
  const float* ea = (const float*)d_in[2];
  const float *Wq[3], *bq[3], *Wk[3], *bk[3], *Wv[3], *bv[3], *We[3], *Wsk[3], *bsk[3];
  for (int L = 0; L < 3; ++L) {
    int b = 3 + 9 * L;
    Wq[L] = (const float*)d_in[b + 0]; bq[L] = (const float*)d_in[b + 1];
    Wk[L] = (const float*)d_in[b + 2]; bk[L] = (const float*)d_in[b + 3];
    Wv[L] = (const float*)d_in[b + 4]; bv[L] = (const float*)d_in[b + 5];
    We[L] = (const float*)d_in[b + 6]; Wsk[L] = (const float*)d_in[b + 7];
    bsk[L] = (const float*)d_in[b + 8];
  }
  const float* gnw = (const float*)d_in[30];
  const float* gnb = (const float*)d_in[31];

  char* p = (char*)d_ws;
  auto alloc = [&](size_t bytes) -> void* {
    void* r = (void*)p;
    p += (bytes + 255) & ~(size_t)255;
    return r;
  };
  float* q_tab = (float*)alloc((size_t)NN * 256 * 4);
  float* k_tab = (float*)alloc((size_t)NN * 256 * 4);
  float* v_tab = (float*)alloc((size_t)NN * 256 * 4);
  float* qt_tab = (float*)alloc((size_t)NN * 256 * 4);
  float* skip_tab = (float*)alloc((size_t)NN * 64 * 4);
  float* h_buf = (float*)alloc((size_t)NN * 64 * 4);
  int* row_ptr = (int*)alloc((size_t)(NN + 1) * 4);
  int* deg = (int*)alloc((size_t)NN * 4);
  int* cursor = (int*)alloc((size_t)NN * 4);
  int* src_sorted = (int*)alloc((size_t)NE * 4);
  int* eid_sorted = (int*)alloc((size_t)NE * 4);
  int* src32 = (int*)alloc((size_t)NE * 4);
  int* dst32 = (int*)alloc((size_t)NE * 4);
  int* flag = (int*)alloc(256);
  float* Wt[3]; float* bb[3]; float* west[3];
  Wt[0] = (float*)alloc((size_t)NCOLS * 128 * 4);
  Wt[1] = (float*)alloc((size_t)NCOLS * 64 * 4);
  Wt[2] = (float*)alloc((size_t)NCOLS * 64 * 4);
  for (int L = 0; L < 3; ++L) bb[L] = (float*)alloc((size_t)NCOLS * 4);
  for (int L = 0; L < 3; ++L) west[L] = (float*)alloc((size_t)16384 * 4);

  // Workspace overflow guard: all-zero output == error 1.65625 signature.
  if ((size_t)(p - (char*)d_ws) > ws_size) {
    hipMemsetAsync(d_out, 0, (size_t)out_size * 4, stream);
    return;
  }

  hipMemsetAsync(deg, 0, (size_t)NN * 4, stream);
  hipMemsetAsync(cursor, 0, (size_t)NN * 4, stream);
  hipMemsetAsync(flag, 0, 4, stream);

  detect_i64<<<8, 256, 0, stream>>>((const int*)ei, flag);
  extract_edges<<<2048, 256, 0, stream>>>(ei, flag, src32, dst32, NE);

  hist_kernel<<<2048, 256, 0, stream>>>(dst32, deg, NE);
  scan_kernel<<<1, 1024, 0, stream>>>(deg, row_ptr, NN);
  scatter_kernel<<<2048, 256, 0, stream>>>(src32, dst32, row_ptr, cursor, src_sorted, eid_sorted, NE);
  sort_lists<<<(NN + 255) / 256, 256, 0, stream>>>(row_ptr, src_sorted, eid_sorted, NN);

  for (int L = 0; L < 3; ++L) {
    int fin = (L == 0) ? 128 : 64;
    prep_wt<<<(NCOLS * fin + 255) / 256, 256, 0, stream>>>(Wq[L], Wk[L], Wv[L], We[L], Wsk[L], Wt[L], fin);
    prep_bias<<<(NCOLS + 255) / 256, 256, 0, stream>>>(bq[L], bk[L], bv[L], We[L], bsk[L], bb[L]);
    prep_west<<<64, 256, 0, stream>>>(We[L], west[L]);
  }

  const float* hin = x;
  for (int L = 0; L < 3; ++L) {
    int fin = (L == 0) ? 128 : 64;
    dim3 g((NN + 127) / 128, 17);
    node_gemm_f32<<<g, 256, 0, stream>>>(hin, Wt[L], bb[L], q_tab, k_tab, v_tab, qt_tab, skip_tab, NN, fin);
    attn_kernel_f32<<<2048, 256, 0, stream>>>(
        row_ptr, src_sorted, eid_sorted, ea, q_tab, k_tab, v_tab, qt_tab,
        skip_tab, west[L], gnw, gnb,
        (L == 2) ? (float*)d_out : h_buf, NN);
    hin = h_buf;
  }
}

// Round 4
// 1777.524 us; speedup vs baseline: 1.1919x; 1.1919x over previous
//
#include <hip/hip_runtime.h>
#include <math.h>

#define NN 50000
#define NE 800000
#define NCOLS 1088   // 256 q | 256 k | 256 v | 256 qt | 64 skip   (cols are h*64+d order)

typedef long long i64;

// ---------------- edge-index dtype probe + extraction ----------------
__global__ void detect_i64(const int* __restrict__ ei32, int* __restrict__ flag) {
  int i = blockIdx.x * blockDim.x + threadIdx.x;
  if (i < 2048) {
    if (ei32[2 * i + 1] != 0) atomicOr(flag, 1);  // 1 -> data is int32
  }
}

__global__ void extract_edges(const void* __restrict__ ei, const int* __restrict__ flag,
                              int* __restrict__ src32, int* __restrict__ dst32, int ne) {
  int is32 = *flag;
  int i = blockIdx.x * blockDim.x + threadIdx.x;
  int st = gridDim.x * blockDim.x;
  if (is32) {
    const int* p = (const int*)ei;
    for (; i < ne; i += st) { src32[i] = p[i]; dst32[i] = p[ne + i]; }
  } else {
    const i64* p = (const i64*)ei;
    for (; i < ne; i += st) { src32[i] = (int)p[i]; dst32[i] = (int)p[ne + i]; }
  }
}

// ---------------- CSR build ----------------
__global__ void hist_kernel(const int* __restrict__ dst, int* __restrict__ deg, int ne) {
  int i = blockIdx.x * blockDim.x + threadIdx.x;
  int st = gridDim.x * blockDim.x;
  for (; i < ne; i += st) atomicAdd(&deg[dst[i]], 1);
}

__global__ void scan_kernel(const int* __restrict__ deg, int* __restrict__ row_ptr, int n) {
  __shared__ int buf[1024];
  int t = threadIdx.x;
  int carry = 0;
  if (t == 0) row_ptr[0] = 0;
  for (int base = 0; base < n; base += 1024) {
    int v = (base + t < n) ? deg[base + t] : 0;
    buf[t] = v;
    __syncthreads();
    for (int off = 1; off < 1024; off <<= 1) {
      int x = (t >= off) ? buf[t - off] : 0;
      __syncthreads();
      buf[t] += x;
      __syncthreads();
    }
    if (base + t < n) row_ptr[base + t + 1] = carry + buf[t];
    carry += buf[1023];
    __syncthreads();
  }
}

__global__ void scatter_kernel(const int* __restrict__ src, const int* __restrict__ dst,
                               const int* __restrict__ row_ptr, int* __restrict__ cursor,
                               int* __restrict__ src_sorted, int* __restrict__ eid_sorted, int ne) {
  int i = blockIdx.x * blockDim.x + threadIdx.x;
  int st = gridDim.x * blockDim.x;
  for (; i < ne; i += st) {
    int d = dst[i];
    int pos = row_ptr[d] + atomicAdd(&cursor[d], 1);
    src_sorted[pos] = src[i];
    eid_sorted[pos] = i;
  }
}

// Deterministic order: sort each node's edge list by eid.
__global__ void sort_lists(const int* __restrict__ row_ptr, int* __restrict__ src_sorted,
                           int* __restrict__ eid_sorted, int n) {
  int node = blockIdx.x * blockDim.x + threadIdx.x;
  if (node >= n) return;
  int beg = row_ptr[node], end = row_ptr[node + 1];
  for (int a = beg + 1; a < end; ++a) {
    int e = eid_sorted[a], s = src_sorted[a];
    int b = a - 1;
    while (b >= beg && eid_sorted[b] > e) {
      eid_sorted[b + 1] = eid_sorted[b];
      src_sorted[b + 1] = src_sorted[b];
      --b;
    }
    eid_sorted[b + 1] = e; src_sorted[b + 1] = s;
  }
}

// ---------------- weight prep (fp32, head-major cols) ----------------
// Wt [col][k]: col<256 q (c=h*64+d), <512 k, <768 v, <1024 qt (h=(c-768)>>6, ce=(c-768)&63), else skip
__global__ void prep_wt(const float* __restrict__ Wq, const float* __restrict__ Wk,
                        const float* __restrict__ Wv, const float* __restrict__ We,
                        const float* __restrict__ Wsk, float* __restrict__ Wt, int fin) {
  int i = blockIdx.x * blockDim.x + threadIdx.x;
  if (i >= NCOLS * fin) return;
  int col = i / fin, k = i % fin;
  float val;
  if (col < 768) {
    const float* W = (col < 256) ? Wq : (col < 512) ? Wk : Wv;
    val = W[k * 256 + (col & 255)];
  } else if (col < 1024) {
    int idx = col - 768; int h = idx >> 6, ce = idx & 63;
    float a = 0.f;
    for (int d = 0; d < 64; ++d) a += Wq[k * 256 + h * 64 + d] * We[ce * 256 + h * 64 + d];
    val = a;
  } else {
    val = Wsk[k * 64 + (col - 1024)];
  }
  Wt[(size_t)col * fin + k] = val;
}

__global__ void prep_bias(const float* __restrict__ bq, const float* __restrict__ bk,
                          const float* __restrict__ bv, const float* __restrict__ We,
                          const float* __restrict__ bsk, float* __restrict__ bb) {
  int col = blockIdx.x * blockDim.x + threadIdx.x;
  if (col >= NCOLS) return;
  float val;
  if (col < 768) {
    const float* b = (col < 256) ? bq : (col < 512) ? bk : bv;
    val = b[col & 255];
  } else if (col < 1024) {
    int idx = col - 768; int h = idx >> 6, ce = idx & 63;
    float a = 0.f;
    for (int d = 0; d < 64; ++d) a += bq[h * 64 + d] * We[ce * 256 + h * 64 + d];
    val = a;
  } else {
    val = bsk[col - 1024];
  }
  bb[col] = val;
}

// ---------------- fp32 node GEMM: out = X[N,fin] @ Wt^T + b ----------------
__global__ __launch_bounds__(256) void node_gemm_f32(
    const float* __restrict__ X, const float* __restrict__ Wt, const float* __restrict__ bb,
    float* __restrict__ q_tab, float* __restrict__ k_tab, float* __restrict__ v_tab,
    float* __restrict__ qt_tab, float* __restrict__ skip_tab, int n, int fin) {
  __shared__ __align__(16) float Xs[128][68];
  __shared__ __align__(16) float Ws[64][68];
  int tid = threadIdx.x;
  int tx = tid & 15, ty = tid >> 4;
  int m0 = blockIdx.x * 128, c0 = blockIdx.y * 64;
  float acc[8][4];
  #pragma unroll
  for (int i = 0; i < 8; ++i)
    #pragma unroll
    for (int j = 0; j < 4; ++j) acc[i][j] = 0.f;

  for (int k0 = 0; k0 < fin; k0 += 64) {
    #pragma unroll
    for (int p = 0; p < 8; ++p) {
      int r = ty + 16 * p;
      float4 xv = make_float4(0.f, 0.f, 0.f, 0.f);
      if (m0 + r < n) xv = *(const float4*)&X[(size_t)(m0 + r) * fin + k0 + tx * 4];
      *(float4*)&Xs[r][tx * 4] = xv;
    }
    #pragma unroll
    for (int p = 0; p < 4; ++p) {
      int r = ty + 16 * p;
      float4 wv = *(const float4*)&Wt[(size_t)(c0 + r) * fin + k0 + tx * 4];
      *(float4*)&Ws[r][tx * 4] = wv;
    }
    __syncthreads();
    #pragma unroll 4
    for (int kk = 0; kk < 64; kk += 4) {
      float4 a[8], b[4];
      #pragma unroll
      for (int i = 0; i < 8; ++i) a[i] = *(const float4*)&Xs[ty + 16 * i][kk];
      #pragma unroll
      for (int j = 0; j < 4; ++j) b[j] = *(const float4*)&Ws[tx + 16 * j][kk];
      #pragma unroll
      for (int i = 0; i < 8; ++i)
        #pragma unroll
        for (int j = 0; j < 4; ++j) {
          acc[i][j] = fmaf(a[i].x, b[j].x, acc[i][j]);
          acc[i][j] = fmaf(a[i].y, b[j].y, acc[i][j]);
          acc[i][j] = fmaf(a[i].z, b[j].z, acc[i][j]);
          acc[i][j] = fmaf(a[i].w, b[j].w, acc[i][j]);
        }
    }
    __syncthreads();
  }
  #pragma unroll
  for (int j = 0; j < 4; ++j) {
    int col = c0 + tx + 16 * j;
    float bias = bb[col];
    #pragma unroll
    for (int i = 0; i < 8; ++i) {
      int row = m0 + ty + 16 * i;
      if (row >= n) continue;
      float val = acc[i][j] + bias;
      if (col < 256)       q_tab[(size_t)row * 256 + col] = val;
      else if (col < 512)  k_tab[(size_t)row * 256 + col - 256] = val;
      else if (col < 768)  v_tab[(size_t)row * 256 + col - 512] = val;
      else if (col < 1024) qt_tab[(size_t)row * 256 + col - 768] = val;
      else                 skip_tab[(size_t)row * 64 + col - 1024] = val;
    }
  }
}

// ---------------- fused attention + post + skip + GN + GELU (fp32, head-major) ----------------
// Lane l: head h=l>>4, channel block i4=(l&15)*4. Per-head dot = 4-level shfl over 16 lanes.
__global__ __launch_bounds__(256, 6) void attn_kernel_f32(
    const int* __restrict__ row_ptr, const int* __restrict__ src_sorted,
    const int* __restrict__ eid_sorted, const float* __restrict__ ea,
    const float* __restrict__ q_tab, const float* __restrict__ k_tab,
    const float* __restrict__ v_tab, const float* __restrict__ qt_tab,
    const float* __restrict__ skip_tab, const float* __restrict__ west,  // = We [64][256]
    const float* __restrict__ gnw, const float* __restrict__ gnb,
    float* __restrict__ out, int n) {
  int tid = threadIdx.x;
  int wave = tid >> 6, lane = tid & 63;
  int node = blockIdx.x * 4 + wave;
  if (node >= n) return;
  int h = lane >> 4;
  int foff = h * 16 + (lane & 15);      // float4 offset within a 256-float row
  const float4* q4p = (const float4*)q_tab;
  const float4* t4p = (const float4*)qt_tab;
  const float4* k4p = (const float4*)k_tab;
  const float4* v4p = (const float4*)v_tab;
  const float4* e4p = (const float4*)ea;
  const float4* w4p = (const float4*)west;

  float4 q4 = q4p[(size_t)node * 64 + foff];
  float4 t4 = t4p[(size_t)node * 64 + foff];

  float m = -INFINITY, s = 0.f;
  float4 av = make_float4(0.f, 0.f, 0.f, 0.f);
  float4 aw = make_float4(0.f, 0.f, 0.f, 0.f);

  int beg = row_ptr[node], end = row_ptr[node + 1];
  float4 kp, vp, ep;
  if (beg < end) {
    int sidx = src_sorted[beg], eid = eid_sorted[beg];
    kp = k4p[(size_t)sidx * 64 + foff];
    vp = v4p[(size_t)sidx * 64 + foff];
    ep = e4p[(size_t)eid * 16 + (lane & 15)];
  }
  for (int j = beg; j < end; ++j) {
    float4 kc = kp, vc = vp, ec = ep;
    if (j + 1 < end) {                       // prefetch next edge (issues before shfl chain)
      int sidx = src_sorted[j + 1], eid = eid_sorted[j + 1];
      kp = k4p[(size_t)sidx * 64 + foff];
      vp = v4p[(size_t)sidx * 64 + foff];
      ep = e4p[(size_t)eid * 16 + (lane & 15)];
    }
    float p = q4.x * kc.x + q4.y * kc.y + q4.z * kc.z + q4.w * kc.w
            + t4.x * ec.x + t4.y * ec.y + t4.z * ec.z + t4.w * ec.w;
    p += __shfl_xor(p, 1);
    p += __shfl_xor(p, 2);
    p += __shfl_xor(p, 4);
    p += __shfl_xor(p, 8);
    p *= 0.125f;
    float d_ = p - m;
    float e_ = __expf(-fabsf(d_));
    float sc = d_ > 0.f ? e_ : 1.f;
    float pp = d_ > 0.f ? 1.f : e_;
    m = fmaxf(m, p);
    s = s * sc + pp;
    av.x = av.x * sc + pp * vc.x; av.y = av.y * sc + pp * vc.y;
    av.z = av.z * sc + pp * vc.z; av.w = av.w * sc + pp * vc.w;
    aw.x = aw.x * sc + pp * ec.x; aw.y = aw.y * sc + pp * ec.y;
    aw.z = aw.z * sc + pp * ec.z; aw.w = aw.w * sc + pp * ec.w;
  }
  float inv = s > 0.f ? 1.f / s : 0.f;
  float4 avn = make_float4(av.x * inv, av.y * inv, av.z * inv, av.w * inv);
  float4 awn = make_float4(aw.x * inv, aw.y * inv, aw.z * inv, aw.w * inv);

  // West matvec: post_h(c) for this head's channel block, awn broadcast within group
  float4 post = make_float4(0.f, 0.f, 0.f, 0.f);
  int gbase = h << 4;
  #pragma unroll 4
  for (int ce4 = 0; ce4 < 16; ++ce4) {
    int srcl = gbase | ce4;
    float wa = __shfl(awn.x, srcl);
    float wb = __shfl(awn.y, srcl);
    float wc = __shfl(awn.z, srcl);
    float wd = __shfl(awn.w, srcl);
    float4 w0 = w4p[(size_t)(ce4 * 4 + 0) * 64 + foff];
    float4 w1 = w4p[(size_t)(ce4 * 4 + 1) * 64 + foff];
    float4 w2 = w4p[(size_t)(ce4 * 4 + 2) * 64 + foff];
    float4 w3 = w4p[(size_t)(ce4 * 4 + 3) * 64 + foff];
    post.x = fmaf(wa, w0.x, post.x); post.y = fmaf(wa, w0.y, post.y);
    post.z = fmaf(wa, w0.z, post.z); post.w = fmaf(wa, w0.w, post.w);
    post.x = fmaf(wb, w1.x, post.x); post.y = fmaf(wb, w1.y, post.y);
    post.z = fmaf(wb, w1.z, post.z); post.w = fmaf(wb, w1.w, post.w);
    post.x = fmaf(wc, w2.x, post.x); post.y = fmaf(wc, w2.y, post.y);
    post.z = fmaf(wc, w2.z, post.z); post.w = fmaf(wc, w2.w, post.w);
    post.x = fmaf(wd, w3.x, post.x); post.y = fmaf(wd, w3.y, post.y);
    post.z = fmaf(wd, w3.z, post.z); post.w = fmaf(wd, w3.w, post.w);
  }

  // Sum avn+post across the 4 head groups (lane bits 4,5)
  float4 tot = make_float4(avn.x + post.x, avn.y + post.y, avn.z + post.z, avn.w + post.w);
  tot.x += __shfl_xor(tot.x, 16); tot.y += __shfl_xor(tot.y, 16);
  tot.z += __shfl_xor(tot.z, 16); tot.w += __shfl_xor(tot.w, 16);
  tot.x += __shfl_xor(tot.x, 32); tot.y += __shfl_xor(tot.y, 32);
  tot.z += __shfl_xor(tot.z, 32); tot.w += __shfl_xor(tot.w, 32);

  // Redistribute: lane c takes component c&3 from lane c>>2 (replicated across groups)
  int srcl = lane >> 2;
  float va = __shfl(tot.x, srcl);
  float vb = __shfl(tot.y, srcl);
  float vc2 = __shfl(tot.z, srcl);
  float vd = __shfl(tot.w, srcl);
  float v01 = (lane & 1) ? vb : va;
  float v23 = (lane & 1) ? vd : vc2;
  float hsum = (lane & 2) ? v23 : v01;

  float val = 0.25f * hsum + skip_tab[(size_t)node * 64 + lane];
  // GroupNorm: groups of 4 consecutive channels = 4-lane groups
  float sm = val + __shfl_xor(val, 1);
  sm += __shfl_xor(sm, 2);
  float mu = sm * 0.25f;
  float dv = val - mu;
  float vq = dv * dv;
  float v2 = vq + __shfl_xor(vq, 1);
  v2 += __shfl_xor(v2, 2);
  float xn = dv * rsqrtf(v2 * 0.25f + 1e-5f);
  float y = xn * gnw[lane] + gnb[lane];
  float g = 0.5f * y * (1.0f + erff(y * 0.70710678118654752f));
  out[(size_t)node * 64 + lane] = g;
}

// ---------------- host ----------------
extern "C" void kernel_launch(void* const* d_in, const int* in_sizes, int n_in,
                              void* d_out, int out_size, void* d_ws, size_t ws_size,
                              hipStream_t stream) {
  (void)in_sizes; (void)n_in;
  const float* x = (const float*)d_in[0];
  const void* ei = d_in[1];
  const float* ea = (const float*)d_in[2];
  const float *Wq[3], *bq[3], *Wk[3], *bk[3], *Wv[3], *bv[3], *We[3], *Wsk[3], *bsk[3];
  for (int L = 0; L < 3; ++L) {
    int b = 3 + 9 * L;
    Wq[L] = (const float*)d_in[b + 0]; bq[L] = (const float*)d_in[b + 1];
    Wk[L] = (const float*)d_in[b + 2]; bk[L] = (const float*)d_in[b + 3];
    Wv[L] = (const float*)d_in[b + 4]; bv[L] = (const float*)d_in[b + 5];
    We[L] = (const float*)d_in[b + 6]; Wsk[L] = (const float*)d_in[b + 7];
    bsk[L] = (const float*)d_in[b + 8];
  }
  const float* gnw = (const float*)d_in[30];
  const float* gnb = (const float*)d_in[31];

  char* p = (char*)d_ws;
  auto alloc = [&](size_t bytes) -> void* {
    void* r = (void*)p;
    p += (bytes + 255) & ~(size_t)255;
    return r;
  };
  float* q_tab = (float*)alloc((size_t)NN * 256 * 4);
  float* k_tab = (float*)alloc((size_t)NN * 256 * 4);
  float* v_tab = (float*)alloc((size_t)NN * 256 * 4);
  float* qt_tab = (float*)alloc((size_t)NN * 256 * 4);
  float* skip_tab = (float*)alloc((size_t)NN * 64 * 4);
  float* h_buf = (float*)alloc((size_t)NN * 64 * 4);
  int* row_ptr = (int*)alloc((size_t)(NN + 1) * 4);
  int* deg = (int*)alloc((size_t)NN * 4);
  int* cursor = (int*)alloc((size_t)NN * 4);
  int* src_sorted = (int*)alloc((size_t)NE * 4);
  int* eid_sorted = (int*)alloc((size_t)NE * 4);
  int* src32 = (int*)alloc((size_t)NE * 4);
  int* dst32 = (int*)alloc((size_t)NE * 4);
  int* flag = (int*)alloc(256);
  float* Wt[3]; float* bb[3];
  Wt[0] = (float*)alloc((size_t)NCOLS * 128 * 4);
  Wt[1] = (float*)alloc((size_t)NCOLS * 64 * 4);
  Wt[2] = (float*)alloc((size_t)NCOLS * 64 * 4);
  for (int L = 0; L < 3; ++L) bb[L] = (float*)alloc((size_t)NCOLS * 4);

  // Workspace overflow guard: all-zero output == error 1.65625 signature.
  if ((size_t)(p - (char*)d_ws) > ws_size) {
    hipMemsetAsync(d_out, 0, (size_t)out_size * 4, stream);
    return;
  }

  hipMemsetAsync(deg, 0, (size_t)NN * 4, stream);
  hipMemsetAsync(cursor, 0, (size_t)NN * 4, stream);
  hipMemsetAsync(flag, 0, 4, stream);

  detect_i64<<<8, 256, 0, stream>>>((const int*)ei, flag);
  extract_edges<<<2048, 256, 0, stream>>>(ei, flag, src32, dst32, NE);

  hist_kernel<<<2048, 256, 0, stream>>>(dst32, deg, NE);
  scan_kernel<<<1, 1024, 0, stream>>>(deg, row_ptr, NN);
  scatter_kernel<<<2048, 256, 0, stream>>>(src32, dst32, row_ptr, cursor, src_sorted, eid_sorted, NE);
  sort_lists<<<(NN + 255) / 256, 256, 0, stream>>>(row_ptr, src_sorted, eid_sorted, NN);

  for (int L = 0; L < 3; ++L) {
    int fin = (L == 0) ? 128 : 64;
    prep_wt<<<(NCOLS * fin + 255) / 256, 256, 0, stream>>>(Wq[L], Wk[L], Wv[L], We[L], Wsk[L], Wt[L], fin);
    prep_bias<<<(NCOLS + 255) / 256, 256, 0, stream>>>(bq[L], bk[L], bv[L], We[L], bsk[L], bb[L]);
  }

  const float* hin = x;
  int ngroups = (NN + 3) / 4;
  for (int L = 0; L < 3; ++L) {
    int fin = (L == 0) ? 128 : 64;
    dim3 g((NN + 127) / 128, 17);
    node_gemm_f32<<<g, 256, 0, stream>>>(hin, Wt[L], bb[L], q_tab, k_tab, v_tab, qt_tab, skip_tab, NN, fin);
    attn_kernel_f32<<<ngroups, 256, 0, stream>>>(
        row_ptr, src_sorted, eid_sorted, ea, q_tab, k_tab, v_tab, qt_tab,
        skip_tab, We[L], gnw, gnb,
        (L == 2) ? (float*)d_out : h_buf, NN);
    hin = h_buf;
  }
}